// Round 12
// baseline (590.799 us; speedup 1.0000x reference)
//
#include <hip/hip_runtime.h>
#include <cmath>

#define NTOK 32768   // 8*4096 tokens
#define EMB  2048
#define NEXP 64
#define TOPK 8
#define KC   64      // K per chunk (2 MFMA k-steps)
#define NCH  (EMB / KC)   // 32
#define TAU  1e-4f   // exact-recompute margin (~60 sigma of limb-GEMM error)

typedef __attribute__((ext_vector_type(8))) short bf16x8;   // 8 bf16 (4 VGPRs)
typedef __attribute__((ext_vector_type(4))) float f32x4;

union U4 { unsigned int u[4]; bf16x8 v; };

// W bf16 limb planes, 768 KB (L2-resident), per chunk:
// g_wl[ch][ ((p*2+kk)*4+q)*512 + er*8 + j ] = bf16 limb p of W[er][ch*64+kk*32+q*8+j]
__device__ unsigned short g_wl[NCH][12288];
// W^T for the exact-redo path, lane-coalesced: g_wt4[(k>>2)*256 + e*4 + (k&3)] = W[e][k]
__device__ float g_wt4[EMB * 64];

static __device__ __forceinline__ float uf(unsigned int x) { return __uint_as_float(x); }
static __device__ __forceinline__ unsigned int fu(float x) { return __float_as_uint(x); }

// ---- pre-kernel: split W into 3 truncated-bf16 limb planes (exact Sterbenz splits)
//      + write coalesced W^T copy for the slow path (unchanged, harness-verified)
__global__ __launch_bounds__(512) void wsplit(const float* __restrict__ W) {
    const int ch  = blockIdx.x;
    const int tid = threadIdx.x;
    const int er = tid >> 3, kk = (tid >> 2) & 1, q = tid & 3;
    const int k0 = ch * KC + kk * 32 + q * 8;
    const float* src = &W[(size_t)er * EMB + k0];
    float x[8];
    #pragma unroll
    for (int j = 0; j < 8; ++j) x[j] = src[j];
    #pragma unroll
    for (int j = 0; j < 8; ++j) {
        const int k = k0 + j;
        g_wt4[(k >> 2) * 256 + er * 4 + (k & 3)] = x[j];
    }
    unsigned int P[3][4];
    #pragma unroll
    for (int m = 0; m < 4; ++m) {
        float x0 = x[2*m], x1 = x[2*m+1];
        unsigned int u0 = fu(x0), u1 = fu(x1);
        P[0][m] = (u0 >> 16) | (u1 & 0xffff0000u);
        float r0 = x0 - uf(u0 & 0xffff0000u), r1 = x1 - uf(u1 & 0xffff0000u);
        unsigned int w0 = fu(r0), w1 = fu(r1);
        P[1][m] = (w0 >> 16) | (w1 & 0xffff0000u);
        float s0 = r0 - uf(w0 & 0xffff0000u), s1 = r1 - uf(w1 & 0xffff0000u);
        P[2][m] = (fu(s0) >> 16) | (fu(s1) & 0xffff0000u);
    }
    #pragma unroll
    for (int p = 0; p < 3; ++p) {
        unsigned short* d = &g_wl[ch][((p*2 + kk)*4 + q)*512 + er*8];
        *(uint4*)(void*)d = make_uint4(P[p][0], P[p][1], P[p][2], P[p][3]);
    }
}

// Wave-independent router: each wave owns 16 tokens x all 64 experts, full K.
// No LDS, no barriers. X reg-staged (dbuf), W limbs direct from L2-resident g_wl.
__global__ __launch_bounds__(256, 2) void router_ws(
    const float* __restrict__ X,   // [NTOK][EMB]
    const float* __restrict__ W,   // [NEXP][EMB]
    const float* __restrict__ Bv,  // [NEXP]
    float* __restrict__ out)       // probs [NTOK][64], then indices [NTOK][8] as f32
{
    const int lane = threadIdx.x & 63;
    const int wv   = threadIdx.x >> 6;           // 0..3
    const int eL   = lane & 15;
    const int q    = lane >> 4;
    const int tok0 = (blockIdx.x * 4 + wv) * 16;

    f32x4 am[4], ac[4];            // per-cc (16 experts each) head + correction acc
    #pragma unroll
    for (int t = 0; t < 4; ++t) {
        am[t] = (f32x4){0.f, 0.f, 0.f, 0.f};
        ac[t] = (f32x4){0.f, 0.f, 0.f, 0.f};
    }

    // lane's A row: token tok0+eL; per chunk reads 32B contiguous at q*8 floats.
    const float* xrow = X + (size_t)(tok0 + eL) * EMB + q * 8;

    float4 xA[2][2], xB[2][2];     // [kk][half] register X buffers
    auto ldX = [&](int ch, float4 (&xv)[2][2]) {
        #pragma unroll
        for (int kk = 0; kk < 2; ++kk) {
            #pragma unroll
            for (int h = 0; h < 2; ++h)
                xv[kk][h] = *(const float4*)&xrow[ch * 64 + kk * 32 + h * 4];
        }
    };

    // one K-chunk: 2 kk-steps x (limb split + 12 W-frag loads + 24 MFMAs)
    auto doChunk = [&](int ch, const float4 (&xv)[2][2]) {
        const unsigned short* wb = &g_wl[ch][0];
        #pragma unroll
        for (int kk = 0; kk < 2; ++kk) {
            const float4 aL = xv[kk][0], aH = xv[kk][1];
            U4 A1, A2, A3;
            const float e0[8] = {aL.x, aL.y, aL.z, aL.w, aH.x, aH.y, aH.z, aH.w};
            #pragma unroll
            for (int m = 0; m < 4; ++m) {
                float x0 = e0[2*m], x1 = e0[2*m+1];
                unsigned int u0 = fu(x0), u1 = fu(x1);
                A1.u[m] = (u0 >> 16) | (u1 & 0xffff0000u);
                float r0 = x0 - uf(u0 & 0xffff0000u), r1 = x1 - uf(u1 & 0xffff0000u);
                unsigned int w0 = fu(r0), w1 = fu(r1);
                A2.u[m] = (w0 >> 16) | (w1 & 0xffff0000u);
                float s0 = r0 - uf(w0 & 0xffff0000u), s1 = r1 - uf(w1 & 0xffff0000u);
                A3.u[m] = (fu(s0) >> 16) | (fu(s1) & 0xffff0000u);
            }
            #pragma unroll
            for (int cc = 0; cc < 4; ++cc) {
                const int fo = q * 512 + (cc * 16 + eL) * 8;      // ushort offset
                const bf16x8 b0 = *(const bf16x8*)(const void*)(wb + (0*2 + kk) * 2048 + fo);
                const bf16x8 b1 = *(const bf16x8*)(const void*)(wb + (1*2 + kk) * 2048 + fo);
                const bf16x8 b2 = *(const bf16x8*)(const void*)(wb + (2*2 + kk) * 2048 + fo);
                am[cc] = __builtin_amdgcn_mfma_f32_16x16x32_bf16(A1.v, b0, am[cc], 0,0,0);
                ac[cc] = __builtin_amdgcn_mfma_f32_16x16x32_bf16(A1.v, b1, ac[cc], 0,0,0);
                ac[cc] = __builtin_amdgcn_mfma_f32_16x16x32_bf16(A2.v, b0, ac[cc], 0,0,0);
                ac[cc] = __builtin_amdgcn_mfma_f32_16x16x32_bf16(A1.v, b2, ac[cc], 0,0,0);
                ac[cc] = __builtin_amdgcn_mfma_f32_16x16x32_bf16(A2.v, b1, ac[cc], 0,0,0);
                ac[cc] = __builtin_amdgcn_mfma_f32_16x16x32_bf16(A3.v, b0, ac[cc], 0,0,0);
            }
        }
    };

    // main loop: unroll-by-2 with named register sets (static indexing, rule #20)
    ldX(0, xA);
    for (int ch = 0; ch < NCH; ch += 2) {
        ldX(ch + 1, xB);               // prefetch odd chunk
        doChunk(ch, xA);
        if (ch + 2 < NCH) ldX(ch + 2, xA);   // prefetch next even chunk
        doChunk(ch + 1, xB);
    }

    // ---- epilogue: fully wave-local (all 64 experts in-register)
    float* probs = out;
    float* idxo  = out + (size_t)NTOK * NEXP;
    float bb[4];
    #pragma unroll
    for (int c = 0; c < 4; ++c) bb[c] = Bv[c * 16 + eL];

    // whole-wave exact f64 redo for margin-critical tokens (coalesced W^T)
    auto slowToken = [&](int Tg) {
        const float* xr = X + (size_t)Tg * EMB;
        double s0 = 0.0, s1 = 0.0, s2 = 0.0, s3 = 0.0;
        for (int k = 0; k < EMB; k += 8) {
            const float4 xa = *(const float4*)&xr[k];       // uniform -> broadcast
            const float4 xb = *(const float4*)&xr[k + 4];
            const float4 wa = *(const float4*)&g_wt4[(k >> 2) * 256 + lane * 4];
            const float4 wb = *(const float4*)&g_wt4[((k >> 2) + 1) * 256 + lane * 4];
            s0 += (double)xa.x * wa.x + (double)xb.x * wb.x;
            s1 += (double)xa.y * wa.y + (double)xb.y * wb.y;
            s2 += (double)xa.z * wa.z + (double)xb.z * wb.z;
            s3 += (double)xa.w * wa.w + (double)xb.w * wb.w;
        }
        double ex = (double)Bv[lane] + ((s0 + s1) + (s2 + s3));
        bool selb = false; int myrank = 0;
        double m0d = 0.0; float ss = 0.f;
        #pragma unroll
        for (int it = 0; it < TOPK; ++it) {
            double bv = selb ? -1.0e300 : ex; int be = lane;
            #pragma unroll
            for (int off = 1; off <= 32; off <<= 1) {
                const double ov = __shfl_xor(bv, off, 64);
                const int    oe = __shfl_xor(be, off, 64);
                if (ov > bv || (ov == bv && oe < be)) { bv = ov; be = oe; }
            }
            if (it == 0) m0d = bv;
            ss += __expf((float)(bv - m0d));
            if (lane == be) { selb = true; myrank = it; }
        }
        probs[(size_t)Tg * NEXP + lane] = selb ? __expf((float)(ex - m0d)) / ss : 0.f;
        if (selb) idxo[(size_t)Tg * TOPK + myrank] = (float)lane;
    };

    // fast top-8 + masked softmax: token (q,i) handled by 16-lane group q
    #pragma unroll
    for (int i = 0; i < 4; ++i) {
        float v[4];
        #pragma unroll
        for (int c = 0; c < 4; ++c) v[c] = (am[c][i] + ac[c][i]) + bb[c];

        unsigned sel = 0;
        float m0 = 0.f, ssum = 0.f, prev = 0.f, mingap = 1e30f;
        int myIdx = 0;
        #pragma unroll
        for (int it = 0; it <= TOPK; ++it) {    // 9 ranks: need gap to rank-8
            float bv = -1e30f; int be = 1 << 30;
            #pragma unroll
            for (int c = 0; c < 4; ++c)
                if (!((sel >> c) & 1) && v[c] > bv) { bv = v[c]; be = c * 16 + eL; }
            float gv = bv; int ge = be;
            #pragma unroll
            for (int off = 1; off <= 8; off <<= 1) {
                const float ov = __shfl_xor(gv, off, 64);
                const int   oe = __shfl_xor(ge, off, 64);
                if (ov > gv || (ov == gv && oe < ge)) { gv = ov; ge = oe; }
            }
            if (it == 0) m0 = gv;
            else mingap = fminf(mingap, prev - gv);
            prev = gv;
            if (it < TOPK) {
                ssum += __expf(gv - m0);
                if ((ge & 15) == eL) sel |= 1u << (ge >> 4);
                if (eL == it) myIdx = ge;
            }
        }
        const int Tg = tok0 + q * 4 + i;
        const float inv = 1.0f / ssum;
        #pragma unroll
        for (int c = 0; c < 4; ++c) {
            const float p = ((sel >> c) & 1) ? __expf(v[c] - m0) * inv : 0.0f;
            probs[(size_t)Tg * NEXP + c * 16 + eL] = p;
        }
        if (eL < TOPK) idxo[(size_t)Tg * TOPK + eL] = (float)myIdx;

        // margin guard: any adjacent gap among ranks 0..8 below TAU -> exact redo
        const unsigned long long fb = __ballot(mingap < TAU);
        for (int q2 = 0; q2 < 4; ++q2)
            if ((fb >> (q2 * 16)) & 1) slowToken(tok0 + q2 * 4 + i);
    }
}

extern "C" void kernel_launch(void* const* d_in, const int* in_sizes, int n_in,
                              void* d_out, int out_size, void* d_ws, size_t ws_size,
                              hipStream_t stream) {
    const float* X = (const float*)d_in[0];
    const float* W = (const float*)d_in[1];
    const float* B = (const float*)d_in[2];
    wsplit<<<NCH, 512, 0, stream>>>(W);
    router_ws<<<NTOK / 64, 256, 0, stream>>>(X, W, B, (float*)d_out);
}

// Round 14
// 539.055 us; speedup vs baseline: 1.0960x; 1.0960x over previous
//
#include <hip/hip_runtime.h>
#include <cmath>

#define NTOK 32768   // 8*4096 tokens
#define EMB  2048
#define NEXP 64
#define TOPK 8
#define BT   128     // tokens per block -> grid 256 = 1 block/CU
#define KC   64      // K per chunk (2 MFMA k-steps)
#define NCH  (EMB / KC)   // 32
#define TAU  1e-4f   // exact-recompute margin (~60 sigma of limb-GEMM error)

typedef __attribute__((ext_vector_type(8))) short bf16x8;   // 8 bf16 (4 VGPRs)
typedef __attribute__((ext_vector_type(4))) float f32x4;

union U4 { unsigned int u[4]; bf16x8 v; };

// W bf16 limb planes, 768 KB (L2-resident once X loads are non-temporal), per chunk:
// g_wl[ch][ ((p*2+kk)*4+q)*512 + er*8 + j ] = bf16 limb p of W[er][ch*64+kk*32+q*8+j]
__device__ unsigned short g_wl[NCH][12288];
// W^T for the exact-redo path, lane-coalesced: g_wt4[(k>>2)*256 + e*4 + (k&3)] = W[e][k]
__device__ float g_wt4[EMB * 64];

static __device__ __forceinline__ float uf(unsigned int x) { return __uint_as_float(x); }
static __device__ __forceinline__ unsigned int fu(float x) { return __float_as_uint(x); }

// ---- pre-kernel: split W into 3 truncated-bf16 limb planes (exact Sterbenz splits)
//      + write coalesced W^T copy for the slow path (unchanged, harness-verified)
__global__ __launch_bounds__(512) void wsplit(const float* __restrict__ W) {
    const int ch  = blockIdx.x;
    const int tid = threadIdx.x;
    const int er = tid >> 3, kk = (tid >> 2) & 1, q = tid & 3;
    const int k0 = ch * KC + kk * 32 + q * 8;
    const float* src = &W[(size_t)er * EMB + k0];
    float x[8];
    #pragma unroll
    for (int j = 0; j < 8; ++j) x[j] = src[j];
    #pragma unroll
    for (int j = 0; j < 8; ++j) {
        const int k = k0 + j;
        g_wt4[(k >> 2) * 256 + er * 4 + (k & 3)] = x[j];
    }
    unsigned int P[3][4];
    #pragma unroll
    for (int m = 0; m < 4; ++m) {
        float x0 = x[2*m], x1 = x[2*m+1];
        unsigned int u0 = fu(x0), u1 = fu(x1);
        P[0][m] = (u0 >> 16) | (u1 & 0xffff0000u);
        float r0 = x0 - uf(u0 & 0xffff0000u), r1 = x1 - uf(u1 & 0xffff0000u);
        unsigned int w0 = fu(r0), w1 = fu(r1);
        P[1][m] = (w0 >> 16) | (w1 & 0xffff0000u);
        float s0 = r0 - uf(w0 & 0xffff0000u), s1 = r1 - uf(w1 & 0xffff0000u);
        P[2][m] = (fu(s0) >> 16) | (fu(s1) & 0xffff0000u);
    }
    #pragma unroll
    for (int p = 0; p < 3; ++p) {
        unsigned short* d = &g_wl[ch][((p*2 + kk)*4 + q)*512 + er*8];
        *(uint4*)(void*)d = make_uint4(P[p][0], P[p][1], P[p][2], P[p][3]);
    }
}

// Hybrid router: per block (512 thr, 8 waves) — each wave owns 16 tokens x all 64
// experts. X per-lane in registers (NON-TEMPORAL loads: keep L2 clean for W).
// W limb planes staged once per block per chunk into LDS via plain loads + ds_write
// (double-buffered, raw s_barrier + lgkmcnt only — X prefetch never drained).
__global__ __launch_bounds__(512, 1) void router_h(
    const float* __restrict__ X,   // [NTOK][EMB]
    const float* __restrict__ W,   // [NEXP][EMB]
    const float* __restrict__ Bv,  // [NEXP]
    float* __restrict__ out)       // probs [NTOK][64], then indices [NTOK][8] as f32
{
    __shared__ __align__(16) unsigned short wbuf[2][12288];   // 48 KB

    const int tid  = threadIdx.x;
    const int lane = tid & 63;
    const int w    = tid >> 6;     // 0..7
    const int eL   = lane & 15;
    const int q    = lane >> 4;
    const int tok0 = blockIdx.x * BT + w * 16;

    f32x4 am[4], ac[4];            // per-cc (16 experts each) head + correction acc
    #pragma unroll
    for (int t = 0; t < 4; ++t) {
        am[t] = (f32x4){0.f, 0.f, 0.f, 0.f};
        ac[t] = (f32x4){0.f, 0.f, 0.f, 0.f};
    }

    // lane's A row: token tok0+eL; per chunk reads 32B contiguous at q*8 floats.
    const float* xrow = X + (size_t)(tok0 + eL) * EMB + q * 8;

    f32x4 xA[4], xB[4];            // [kk*2+h] register X buffers (nt loads)
    auto ldX = [&](int ch, f32x4 (&xv)[4]) {
        #pragma unroll
        for (int kk = 0; kk < 2; ++kk)
            #pragma unroll
            for (int h = 0; h < 2; ++h)
                xv[kk*2+h] = __builtin_nontemporal_load(
                    (const f32x4*)(xrow + ch * 64 + kk * 32 + h * 4));
    };

    // W stage: 3 x 16B per thread, g_wl[ch] copied linearly into wbuf[b]
    uint4 wr0, wr1, wr2;
    auto GloadW = [&](int ch) {
        const uint4* src = (const uint4*)(const void*)&g_wl[ch][0];
        wr0 = src[tid];
        wr1 = src[tid + 512];
        wr2 = src[tid + 1024];
    };
    auto putW = [&](int b) {       // compiler auto-waits the wr register deps
        uint4* dst = (uint4*)(void*)&wbuf[b][0];
        dst[tid]        = wr0;
        dst[tid + 512]  = wr1;
        dst[tid + 1024] = wr2;
    };

    // one K-chunk: 2 kk-steps x (limb split + 12 LDS frag reads + 24 MFMAs)
    auto doChunk = [&](int b, const f32x4 (&xv)[4]) {
        const unsigned short* wb2 = &wbuf[b][0];
        #pragma unroll
        for (int kk = 0; kk < 2; ++kk) {
            const f32x4 aL = xv[kk*2], aH = xv[kk*2+1];
            U4 A1, A2, A3;
            const float e0[8] = {aL.x, aL.y, aL.z, aL.w, aH.x, aH.y, aH.z, aH.w};
            #pragma unroll
            for (int m = 0; m < 4; ++m) {
                float x0 = e0[2*m], x1 = e0[2*m+1];
                unsigned int u0 = fu(x0), u1 = fu(x1);
                A1.u[m] = (u0 >> 16) | (u1 & 0xffff0000u);
                float r0 = x0 - uf(u0 & 0xffff0000u), r1 = x1 - uf(u1 & 0xffff0000u);
                unsigned int w0 = fu(r0), w1 = fu(r1);
                A2.u[m] = (w0 >> 16) | (w1 & 0xffff0000u);
                float s0 = r0 - uf(w0 & 0xffff0000u), s1 = r1 - uf(w1 & 0xffff0000u);
                A3.u[m] = (fu(s0) >> 16) | (fu(s1) & 0xffff0000u);
            }
            #pragma unroll
            for (int cc = 0; cc < 4; ++cc) {
                const int fo = q * 512 + (cc * 16 + eL) * 8;      // ushort offset
                const bf16x8 b0 = *(const bf16x8*)(const void*)(wb2 + (0*2 + kk) * 2048 + fo);
                const bf16x8 b1 = *(const bf16x8*)(const void*)(wb2 + (1*2 + kk) * 2048 + fo);
                const bf16x8 b2 = *(const bf16x8*)(const void*)(wb2 + (2*2 + kk) * 2048 + fo);
                am[cc] = __builtin_amdgcn_mfma_f32_16x16x32_bf16(A1.v, b0, am[cc], 0,0,0);
                ac[cc] = __builtin_amdgcn_mfma_f32_16x16x32_bf16(A1.v, b1, ac[cc], 0,0,0);
                ac[cc] = __builtin_amdgcn_mfma_f32_16x16x32_bf16(A2.v, b0, ac[cc], 0,0,0);
                ac[cc] = __builtin_amdgcn_mfma_f32_16x16x32_bf16(A1.v, b2, ac[cc], 0,0,0);
                ac[cc] = __builtin_amdgcn_mfma_f32_16x16x32_bf16(A2.v, b1, ac[cc], 0,0,0);
                ac[cc] = __builtin_amdgcn_mfma_f32_16x16x32_bf16(A3.v, b0, ac[cc], 0,0,0);
            }
        }
    };

    // ---- prologue: chunk 0 staged, barrier (lgkm only — no vmcnt drain ever)
    GloadW(0);
    ldX(0, xA);
    putW(0);
    asm volatile("s_waitcnt lgkmcnt(0)" ::: "memory");
    __builtin_amdgcn_s_barrier();
    asm volatile("" ::: "memory");

    // ---- main loop, unroll-2: chunk ch in wbuf[ch&1]; prefetch 1 chunk ahead
    for (int ch = 0; ch < NCH; ch += 2) {
        ldX(ch + 1, xB);
        GloadW(ch + 1);
        doChunk(0, xA);
        putW(1);
        asm volatile("s_waitcnt lgkmcnt(0)" ::: "memory");
        __builtin_amdgcn_s_barrier();
        asm volatile("" ::: "memory");

        if (ch + 2 < NCH) { ldX(ch + 2, xA); GloadW(ch + 2); }
        doChunk(1, xB);
        if (ch + 2 < NCH) {
            putW(0);
            asm volatile("s_waitcnt lgkmcnt(0)" ::: "memory");
        }
        __builtin_amdgcn_s_barrier();
        asm volatile("" ::: "memory");
    }

    // ---- epilogue: fully wave-local (all 64 experts in-register)
    float* probs = out;
    float* idxo  = out + (size_t)NTOK * NEXP;
    float bb[4];
    #pragma unroll
    for (int c = 0; c < 4; ++c) bb[c] = Bv[c * 16 + eL];

    // whole-wave exact f64 redo for margin-critical tokens (coalesced W^T)
    auto slowToken = [&](int Tg) {
        const float* xr = X + (size_t)Tg * EMB;
        double s0 = 0.0, s1 = 0.0, s2 = 0.0, s3 = 0.0;
        for (int k = 0; k < EMB; k += 8) {
            const float4 xa = *(const float4*)&xr[k];       // uniform -> broadcast
            const float4 xb = *(const float4*)&xr[k + 4];
            const float4 wa = *(const float4*)&g_wt4[(k >> 2) * 256 + lane * 4];
            const float4 wb = *(const float4*)&g_wt4[((k >> 2) + 1) * 256 + lane * 4];
            s0 += (double)xa.x * wa.x + (double)xb.x * wb.x;
            s1 += (double)xa.y * wa.y + (double)xb.y * wb.y;
            s2 += (double)xa.z * wa.z + (double)xb.z * wb.z;
            s3 += (double)xa.w * wa.w + (double)xb.w * wb.w;
        }
        double ex = (double)Bv[lane] + ((s0 + s1) + (s2 + s3));
        bool selb = false; int myrank = 0;
        double m0d = 0.0; float ss = 0.f;
        #pragma unroll
        for (int it = 0; it < TOPK; ++it) {
            double bv = selb ? -1.0e300 : ex; int be = lane;
            #pragma unroll
            for (int off = 1; off <= 32; off <<= 1) {
                const double ov = __shfl_xor(bv, off, 64);
                const int    oe = __shfl_xor(be, off, 64);
                if (ov > bv || (ov == bv && oe < be)) { bv = ov; be = oe; }
            }
            if (it == 0) m0d = bv;
            ss += __expf((float)(bv - m0d));
            if (lane == be) { selb = true; myrank = it; }
        }
        probs[(size_t)Tg * NEXP + lane] = selb ? __expf((float)(ex - m0d)) / ss : 0.f;
        if (selb) idxo[(size_t)Tg * TOPK + myrank] = (float)lane;
    };

    // fast top-8 + masked softmax: token (q,i) handled by 16-lane group q
    #pragma unroll
    for (int i = 0; i < 4; ++i) {
        float v[4];
        #pragma unroll
        for (int c = 0; c < 4; ++c) v[c] = (am[c][i] + ac[c][i]) + bb[c];

        unsigned sel = 0;
        float m0 = 0.f, ssum = 0.f, prev = 0.f, mingap = 1e30f;
        int myIdx = 0;
        #pragma unroll
        for (int it = 0; it <= TOPK; ++it) {    // 9 ranks: need gap to rank-8
            float bv = -1e30f; int be = 1 << 30;
            #pragma unroll
            for (int c = 0; c < 4; ++c)
                if (!((sel >> c) & 1) && v[c] > bv) { bv = v[c]; be = c * 16 + eL; }
            float gv = bv; int ge = be;
            #pragma unroll
            for (int off = 1; off <= 8; off <<= 1) {
                const float ov = __shfl_xor(gv, off, 64);
                const int   oe = __shfl_xor(ge, off, 64);
                if (ov > gv || (ov == gv && oe < ge)) { gv = ov; ge = oe; }
            }
            if (it == 0) m0 = gv;
            else mingap = fminf(mingap, prev - gv);
            prev = gv;
            if (it < TOPK) {
                ssum += __expf(gv - m0);
                if ((ge & 15) == eL) sel |= 1u << (ge >> 4);
                if (eL == it) myIdx = ge;
            }
        }
        const int Tg = tok0 + q * 4 + i;
        const float inv = 1.0f / ssum;
        #pragma unroll
        for (int c = 0; c < 4; ++c) {
            const float p = ((sel >> c) & 1) ? __expf(v[c] - m0) * inv : 0.0f;
            probs[(size_t)Tg * NEXP + c * 16 + eL] = p;
        }
        if (eL < TOPK) idxo[(size_t)Tg * TOPK + eL] = (float)myIdx;

        // margin guard: any adjacent gap among ranks 0..8 below TAU -> exact redo
        const unsigned long long fb = __ballot(mingap < TAU);
        for (int q2 = 0; q2 < 4; ++q2)
            if ((fb >> (q2 * 16)) & 1) slowToken(tok0 + q2 * 4 + i);
    }
}

extern "C" void kernel_launch(void* const* d_in, const int* in_sizes, int n_in,
                              void* d_out, int out_size, void* d_ws, size_t ws_size,
                              hipStream_t stream) {
    const float* X = (const float*)d_in[0];
    const float* W = (const float*)d_in[1];
    const float* B = (const float*)d_in[2];
    wsplit<<<NCH, 512, 0, stream>>>(W);
    router_h<<<NTOK / BT, 512, 0, stream>>>(X, W, B, (float*)d_out);
}